// Round 13
// baseline (179.553 us; speedup 1.0000x reference)
//
#include <hip/hip_runtime.h>
#include <hip/hip_bf16.h>

#define B_    8
#define N_    2048
#define DIN_  512
#define DOUT_ 256
#define NBUCK 20

typedef __attribute__((ext_vector_type(8))) short  short8;
typedef __attribute__((ext_vector_type(4))) float  floatx4;

__device__ __forceinline__ unsigned short f2b(float f) {
    __hip_bfloat16 h = __float2bfloat16(f);
    unsigned short u;
    __builtin_memcpy(&u, &h, 2);
    return u;
}

__device__ __forceinline__ void load_lds16(const unsigned short* g, unsigned short* l) {
    __builtin_amdgcn_global_load_lds(
        (const __attribute__((address_space(1))) unsigned int*)g,
        (__attribute__((address_space(3))) unsigned int*)l, 16, 0, 0);
}

// fast 2^x — bare v_exp_f32 (ISA: D = 2^S0).
__device__ __forceinline__ float fexp2(float x) {
    float r;
    asm("v_exp_f32 %0, %1" : "=v"(r) : "v"(x));
    return r;
}

// ---------------- prep r15: GEMV-only, deep-MLP ------------------------------
__global__ __launch_bounds__(256) void prep_kernel(
    const float* __restrict__ Wv, const float* __restrict__ Ws,
    const float* __restrict__ bv,
    float* __restrict__ wvs, float* __restrict__ bvs) {
    const int blk = blockIdx.x, tid = threadIdx.x;
    __shared__ float wsl[DOUT_];
    wsl[tid] = Ws[tid];
    __syncthreads();
    if (tid < 128) {
        int d = blk * 128 + tid;
        float s0 = 0.f, s1 = 0.f, s2 = 0.f, s3 = 0.f;
#pragma unroll 8
        for (int o = 0; o < DOUT_; o += 4) {
            s0 += Wv[(size_t)(o + 0) * DIN_ + d] * wsl[o + 0];
            s1 += Wv[(size_t)(o + 1) * DIN_ + d] * wsl[o + 1];
            s2 += Wv[(size_t)(o + 2) * DIN_ + d] * wsl[o + 2];
            s3 += Wv[(size_t)(o + 3) * DIN_ + d] * wsl[o + 3];
        }
        wvs[d] = (s0 + s1) + (s2 + s3);
    }
    if (blk == 0 && tid < 64) {
        float bb = wsl[tid] * bv[tid] + wsl[tid + 64] * bv[tid + 64] +
                   wsl[tid + 128] * bv[tid + 128] + wsl[tid + 192] * bv[tid + 192];
        for (int off = 1; off < 64; off <<= 1) bb += __shfl_xor(bb, off, 64);
        if (tid == 0) *bvs = bb;
    }
}

// ---------------- x -> bf16, fused vw = x . wvs + bvs; + Wq/Wk -> bf16 -------
__global__ __launch_bounds__(256) void cvt_x_kernel(const float* __restrict__ x,
                                                    const float* __restrict__ wvs,
                                                    const float* __restrict__ bvs,
                                                    const float* __restrict__ wq,
                                                    const float* __restrict__ wk,
                                                    unsigned short* __restrict__ xb,
                                                    unsigned short* __restrict__ wdst,
                                                    float* __restrict__ vw) {
    int tid = threadIdx.x;
    if (blockIdx.x >= 4096) {
        int i = ((blockIdx.x - 4096) * 256 + tid) * 8;  // 0 .. 262144-8
        const float* src = (i < 131072) ? (wq + i) : (wk + (i - 131072));
        float4 a = *(const float4*)(src);
        float4 b = *(const float4*)(src + 4);
        uint4 r;
        r.x = f2b(a.x) | ((unsigned)f2b(a.y) << 16);
        r.y = f2b(a.z) | ((unsigned)f2b(a.w) << 16);
        r.z = f2b(b.x) | ((unsigned)f2b(b.y) << 16);
        r.w = f2b(b.z) | ((unsigned)f2b(b.w) << 16);
        *(uint4*)(wdst + i) = r;
        return;
    }
    int wave = tid >> 6, lane = tid & 63;
    int row = blockIdx.x * 4 + wave;
    size_t base = (size_t)row * DIN_ + lane * 8;
    float4 a = *(const float4*)(x + base);
    float4 b = *(const float4*)(x + base + 4);
    float4 wa = *(const float4*)(wvs + lane * 8);
    float4 wb = *(const float4*)(wvs + lane * 8 + 4);
    uint4 r;
    r.x = f2b(a.x) | ((unsigned)f2b(a.y) << 16);
    r.y = f2b(a.z) | ((unsigned)f2b(a.w) << 16);
    r.z = f2b(b.x) | ((unsigned)f2b(b.y) << 16);
    r.w = f2b(b.z) | ((unsigned)f2b(b.w) << 16);
    *(uint4*)(xb + base) = r;
    float d = a.x * wa.x + a.y * wa.y + a.z * wa.z + a.w * wa.w +
              b.x * wb.x + b.y * wb.y + b.z * wb.z + b.w * wb.w;
    for (int off = 1; off < 64; off <<= 1) d += __shfl_xor(d, off, 64);
    if (lane == 0) vw[row] = d + *bvs;  // bvs folded in HERE (only here)
}

// ---------------- Q,K GEMM — r14: BK=64 double-buffered 2-phase pipeline -----
__global__ __launch_bounds__(256, 2) void qkv_kernel(
    const unsigned short* __restrict__ xb, const unsigned short* __restrict__ wb,
    const float* __restrict__ bq, const float* __restrict__ bk,
    unsigned short* __restrict__ qo, unsigned short* __restrict__ ko) {
    __shared__ unsigned short alds[2][128 * 64];  // 16 KB per buffer
    __shared__ unsigned short blds[2][128 * 64];  // total 64 KB -> 2 blocks/CU
    const int g = blockIdx.x;
    const int xcd = g & 7, t2 = g >> 3;
    const int colBlk = t2 & 3, rowGrp = t2 >> 2;
    const int rowBlk = rowGrp * 8 + xcd;
    const int tid = threadIdx.x;
    const int wave = tid >> 6, lane = tid & 63, quad = lane >> 4, l16 = lane & 15;
    const int wr = wave >> 1, wc = wave & 1;
    const int row0 = rowBlk * 128, col0 = colBlk * 128;
    const int sw3 = l16 & 7;

    floatx4 acc[4][4];
#pragma unroll
    for (int i = 0; i < 4; ++i)
#pragma unroll
        for (int j = 0; j < 4; ++j) acc[i][j] = (floatx4){0.f, 0.f, 0.f, 0.f};

    const int gseg = (lane & 7) ^ (lane >> 3);
    const unsigned short* ag = xb + (size_t)(row0 + wave * 8 + (lane >> 3)) * DIN_ + gseg * 8;
    const unsigned short* bg = wb + (size_t)(col0 + wave * 8 + (lane >> 3)) * DIN_ + gseg * 8;

    // prologue: stage K-step 0 into buffer 0
#pragma unroll
    for (int i = 0; i < 4; ++i) {
        load_lds16(ag + (size_t)i * 32 * DIN_, &alds[0][wave * 512 + i * 2048]);
        load_lds16(bg + (size_t)i * 32 * DIN_, &blds[0][wave * 512 + i * 2048]);
    }
    __syncthreads();

#pragma unroll 1
    for (int t = 0; t < 8; ++t) {
        const unsigned short* al = (t & 1) ? alds[1] : alds[0];
        const unsigned short* bl = (t & 1) ? blds[1] : blds[0];
        unsigned short* aln = (t & 1) ? &alds[0][0] : &alds[1][0];
        unsigned short* bln = (t & 1) ? &blds[0][0] : &blds[1][0];
        if (t < 7) {
            size_t koff = (size_t)(t + 1) * 64;
#pragma unroll
            for (int i = 0; i < 4; ++i) {
                load_lds16(ag + (size_t)i * 32 * DIN_ + koff, aln + wave * 512 + i * 2048);
                load_lds16(bg + (size_t)i * 32 * DIN_ + koff, bln + wave * 512 + i * 2048);
            }
        }
#pragma unroll
        for (int h = 0; h < 2; ++h) {
            short8 af[4], bf[4];
#pragma unroll
            for (int f = 0; f < 4; ++f) {
                int ar = wr * 64 + f * 16 + l16;
                int br = wc * 64 + f * 16 + l16;
                int s  = (h * 4 + quad) ^ sw3;  // read-side swizzle (row&7 == l16&7)
                af[f] = *(const short8*)&al[(size_t)ar * 64 + s * 8];
                bf[f] = *(const short8*)&bl[(size_t)br * 64 + s * 8];
            }
#pragma unroll
            for (int i = 0; i < 4; ++i)
#pragma unroll
                for (int j = 0; j < 4; ++j)
                    acc[i][j] = __builtin_amdgcn_mfma_f32_16x16x32_bf16(af[i], bf[j], acc[i][j], 0, 0, 0);
        }
        __syncthreads();
    }

#pragma unroll
    for (int j = 0; j < 4; ++j) {
        int col = col0 + wc * 64 + j * 16 + l16;
        unsigned short* dst = (col < 256) ? qo : ko;
        float bias = (col < 256) ? bq[col] : bk[col - 256];
        int c = col & 255;
#pragma unroll
        for (int i = 0; i < 4; ++i)
#pragma unroll
            for (int r = 0; r < 4; ++r) {
                int row = row0 + wr * 64 + i * 16 + quad * 4 + r;
                dst[(size_t)row * DOUT_ + c] = f2b(acc[i][j][r] + bias);
            }
    }
}

// ---------------- gated flash attention — r26: direct-L2 K, zero barriers ----
// Common-mistake #7: per-XCD K working set = 1MB (32 blocks share b=g&7),
// L2-resident -> the LDS staging (DMA queue + 33 vmcnt-draining barriers +
// 128KB kbuf) was pure overhead. r26 reads kf fragments DIRECTLY from global
// (L1-resident per wave: 16KB/chunk working set). kf = K[row][c*32+quad*8]
// is byte-identical fragment semantics to the verified LDS path (read XOR
// undid staging XOR exactly). ZERO __syncthreads in the main loop -> the
// sibling wave on each SIMD free-runs and covers MFMA/gate/load latency
// (what r24 sought via 2 blocks, without halving amortization). cf-halves
// sequential to keep live regs ~120 < the twice-confirmed 128 wall.
// LDS 133KB -> ~5KB. Geometry/arithmetic otherwise r20 (verified).
__global__ __launch_bounds__(512, 2) void attn_kernel(
    const unsigned short* __restrict__ q, const unsigned short* __restrict__ k,
    const float* __restrict__ vw, const int* __restrict__ pr,
    const float* __restrict__ rank_emb, const float* __restrict__ rank_w,
    const float* __restrict__ bs, float* __restrict__ out) {
    const int g = blockIdx.x;
    const int b = g & 7, rblk = g >> 3;
    const int tid = threadIdx.x, wave = tid >> 6, lane = tid & 63;
    const int quad = lane >> 4, l16 = lane & 15;
    const int n0 = rblk * 64;
    const int rg = wave >> 2, ch = wave & 3;  // 2 row-groups x 4 col-quarters

    __shared__ float gtab_r[NBUCK * 32];      // x32 replicated: bank = lane&31
    __shared__ float lL[8][32], wdL[8][32];

    for (int t = tid; t < NBUCK * 32; t += 512)  // scale * log2e folded in
        gtab_r[t] = 0.0625f * 1.44269504f /
                    (1.f + __expf(-rank_w[0] * rank_emb[t >> 5]));
    __syncthreads();                          // gtab visible (only pre-loop barrier)

    const unsigned short* qb = q + (size_t)b * N_ * DOUT_;
    const unsigned short* kb = k + (size_t)b * N_ * DOUT_;
    const float* vwb = vw + b * N_;
    const int* prb = pr + b * N_;
    const int l31 = lane & 31;

    // Q fragments: rows n0 + rg*32 + a*16 + l16 (a=0,1) — 64 VGPRs
    short8 qf[2][8];
#pragma unroll
    for (int a = 0; a < 2; ++a)
#pragma unroll
        for (int c = 0; c < 8; ++c)
            qf[a][c] = *(const short8*)(qb + (size_t)(n0 + rg * 32 + a * 16 + l16) * DOUT_ + c * 32 + quad * 8);

    float prn5[2][4];
#pragma unroll
    for (int a = 0; a < 2; ++a)
#pragma unroll
        for (int r = 0; r < 4; ++r)
            prn5[a][r] = (float)prb[n0 + rg * 32 + a * 16 + quad * 4 + r] * 0.2f;

    float lacc[2][4], wacc[2][4];
#pragma unroll
    for (int a = 0; a < 2; ++a)
#pragma unroll
        for (int r = 0; r < 4; ++r) { lacc[a][r] = 0.f; wacc[a][r] = 0.f; }

    // direct K fragment bases: cf=0 row = ch*32 + l16; cf=1 row = +16.
    // fragment = K[row][c*32 + quad*8 .. +8] — same as the verified LDS read.
    const unsigned short* kc0 = kb + (size_t)(ch * 32 + l16) * DOUT_ + quad * 8;
    const unsigned short* kc1 = kc0 + (size_t)16 * DOUT_;
    const int colq = ch * 32 + l16;  // +16 for cf=1

    // ---- main loop: NO barriers. 16 chunks of 128 k-rows. -------------------
#pragma unroll 1
    for (int j = 0; j < 16; ++j) {
        const size_t jb = (size_t)j * 128 * DOUT_;
        int   pm0 = prb[j * 128 + colq], pm1 = prb[j * 128 + colq + 16];
        float w0  = vwb[j * 128 + colq], w1  = vwb[j * 128 + colq + 16];

        floatx4 s0[2], s1[2];
        s0[0] = (floatx4){0.f, 0.f, 0.f, 0.f}; s0[1] = s0[0];
        s1[0] = s0[0]; s1[1] = s0[0];
        __builtin_amdgcn_s_setprio(1);
#pragma unroll
        for (int c = 0; c < 8; ++c) {
            short8 kf = *(const short8*)(kc0 + jb + c * 32);
            s0[0] = __builtin_amdgcn_mfma_f32_16x16x32_bf16(qf[0][c], kf, s0[0], 0, 0, 0);
            s0[1] = __builtin_amdgcn_mfma_f32_16x16x32_bf16(qf[1][c], kf, s0[1], 0, 0, 0);
        }
#pragma unroll
        for (int c = 0; c < 8; ++c) {
            short8 kf = *(const short8*)(kc1 + jb + c * 32);
            s1[0] = __builtin_amdgcn_mfma_f32_16x16x32_bf16(qf[0][c], kf, s1[0], 0, 0, 0);
            s1[1] = __builtin_amdgcn_mfma_f32_16x16x32_bf16(qf[1][c], kf, s1[1], 0, 0, 0);
        }
        __builtin_amdgcn_s_setprio(0);

        float pm5_0 = (float)pm0 * 0.2f, pm5_1 = (float)pm1 * 0.2f;
#pragma unroll
        for (int a = 0; a < 2; ++a)
#pragma unroll
            for (int r = 0; r < 4; ++r) {
                float d0 = fabsf(prn5[a][r] - pm5_0);
                int i0 = (int)fminf(d0, 19.0f);
                float p0 = fexp2(s0[a][r] * gtab_r[i0 * 32 + l31]);
                lacc[a][r] += p0;
                wacc[a][r] += p0 * w0;
                float d1 = fabsf(prn5[a][r] - pm5_1);
                int i1 = (int)fminf(d1, 19.0f);
                float p1 = fexp2(s1[a][r] * gtab_r[i1 * 32 + l31]);
                lacc[a][r] += p1;
                wacc[a][r] += p1 * w1;
            }
    }

    // merge partials over the 16 column-lanes
#pragma unroll
    for (int off = 1; off < 16; off <<= 1) {
#pragma unroll
        for (int a = 0; a < 2; ++a)
#pragma unroll
            for (int r = 0; r < 4; ++r) {
                lacc[a][r] += __shfl_xor(lacc[a][r], off, 64);
                wacc[a][r] += __shfl_xor(wacc[a][r], off, 64);
            }
    }
    if (l16 == 0) {
#pragma unroll
        for (int a = 0; a < 2; ++a)
#pragma unroll
            for (int r = 0; r < 4; ++r) {
                int row = a * 16 + quad * 4 + r;   // 0..31 within wave's rows
                lL[wave][row]  = lacc[a][r];
                wdL[wave][row] = wacc[a][r];
            }
    }
    __syncthreads();
    if (tid < 64) {
        int rg2 = tid >> 5, sub = tid & 31;
        float l = 0.f, wd = 0.f;
#pragma unroll
        for (int c2 = 0; c2 < 4; ++c2) {
            l  += lL[rg2 * 4 + c2][sub];
            wd += wdL[rg2 * 4 + c2][sub];
        }
        float logit = wd / l + bs[0];   // bvs already inside vw
        out[(size_t)b * N_ + n0 + tid] = 1.f / (1.f + __expf(-logit));
    }
}

// ---------------- launch ----------------
extern "C" void kernel_launch(void* const* d_in, const int* in_sizes, int n_in,
                              void* d_out, int out_size, void* d_ws, size_t ws_size,
                              hipStream_t stream) {
    const float* x   = (const float*)d_in[0];
    const int*   pr  = (const int*)d_in[1];
    const float* Wq  = (const float*)d_in[2];
    const float* bq  = (const float*)d_in[3];
    const float* Wk  = (const float*)d_in[4];
    const float* bk  = (const float*)d_in[5];
    const float* Wv  = (const float*)d_in[6];
    const float* bv  = (const float*)d_in[7];
    const float* Ws  = (const float*)d_in[8];
    const float* bs  = (const float*)d_in[9];
    const float* remb = (const float*)d_in[10];
    const float* rw   = (const float*)d_in[11];
    float* out = (float*)d_out;

    char* ws = (char*)d_ws;
    unsigned short* xb  = (unsigned short*)ws;                    // 16,777,216 B
    unsigned short* wb  = (unsigned short*)(ws + 16777216);       //    524,288 B
    unsigned short* q   = (unsigned short*)(ws + 17301504);       //  8,388,608 B
    unsigned short* kk  = (unsigned short*)(ws + 25690112);       //  8,388,608 B
    float*          vwp = (float*)(ws + 34078720);                //     65,536 B
    float*          wvs = (float*)(ws + 34144256);                //      2,048 B
    float*          bvs = (float*)(ws + 34146304);                //          4 B

    hipLaunchKernelGGL(prep_kernel, dim3(4), dim3(256), 0, stream,
                       Wv, Ws, bv, wvs, bvs);
    hipLaunchKernelGGL(cvt_x_kernel, dim3(4224), dim3(256), 0, stream,
                       x, wvs, bvs, Wq, Wk, xb, wb, vwp);
    hipLaunchKernelGGL(qkv_kernel, dim3(512), dim3(256), 0, stream,
                       xb, wb, bq, bk, q, kk);
    hipLaunchKernelGGL(attn_kernel, dim3(256), dim3(512), 0, stream,
                       q, kk, vwp, pr, remb, rw, bs, out);
}

// Round 14
// 144.624 us; speedup vs baseline: 1.2415x; 1.2415x over previous
//
#include <hip/hip_runtime.h>
#include <hip/hip_bf16.h>

#define B_    8
#define N_    2048
#define DIN_  512
#define DOUT_ 256
#define NBUCK 20

typedef __attribute__((ext_vector_type(8))) short  short8;
typedef __attribute__((ext_vector_type(4))) float  floatx4;

__device__ __forceinline__ unsigned short f2b(float f) {
    __hip_bfloat16 h = __float2bfloat16(f);
    unsigned short u;
    __builtin_memcpy(&u, &h, 2);
    return u;
}

__device__ __forceinline__ void load_lds16(const unsigned short* g, unsigned short* l) {
    __builtin_amdgcn_global_load_lds(
        (const __attribute__((address_space(1))) unsigned int*)g,
        (__attribute__((address_space(3))) unsigned int*)l, 16, 0, 0);
}

// fast 2^x — bare v_exp_f32 (ISA: D = 2^S0).
__device__ __forceinline__ float fexp2(float x) {
    float r;
    asm("v_exp_f32 %0, %1" : "=v"(r) : "v"(x));
    return r;
}

// ---------------- prep r15: GEMV-only, deep-MLP ------------------------------
__global__ __launch_bounds__(256) void prep_kernel(
    const float* __restrict__ Wv, const float* __restrict__ Ws,
    const float* __restrict__ bv,
    float* __restrict__ wvs, float* __restrict__ bvs) {
    const int blk = blockIdx.x, tid = threadIdx.x;
    __shared__ float wsl[DOUT_];
    wsl[tid] = Ws[tid];
    __syncthreads();
    if (tid < 128) {
        int d = blk * 128 + tid;
        float s0 = 0.f, s1 = 0.f, s2 = 0.f, s3 = 0.f;
#pragma unroll 8
        for (int o = 0; o < DOUT_; o += 4) {
            s0 += Wv[(size_t)(o + 0) * DIN_ + d] * wsl[o + 0];
            s1 += Wv[(size_t)(o + 1) * DIN_ + d] * wsl[o + 1];
            s2 += Wv[(size_t)(o + 2) * DIN_ + d] * wsl[o + 2];
            s3 += Wv[(size_t)(o + 3) * DIN_ + d] * wsl[o + 3];
        }
        wvs[d] = (s0 + s1) + (s2 + s3);
    }
    if (blk == 0 && tid < 64) {
        float bb = wsl[tid] * bv[tid] + wsl[tid + 64] * bv[tid + 64] +
                   wsl[tid + 128] * bv[tid + 128] + wsl[tid + 192] * bv[tid + 192];
        for (int off = 1; off < 64; off <<= 1) bb += __shfl_xor(bb, off, 64);
        if (tid == 0) *bvs = bb;
    }
}

// ---------------- x -> bf16, fused vw = x . wvs + bvs; + Wq/Wk -> bf16 -------
__global__ __launch_bounds__(256) void cvt_x_kernel(const float* __restrict__ x,
                                                    const float* __restrict__ wvs,
                                                    const float* __restrict__ bvs,
                                                    const float* __restrict__ wq,
                                                    const float* __restrict__ wk,
                                                    unsigned short* __restrict__ xb,
                                                    unsigned short* __restrict__ wdst,
                                                    float* __restrict__ vw) {
    int tid = threadIdx.x;
    if (blockIdx.x >= 4096) {
        int i = ((blockIdx.x - 4096) * 256 + tid) * 8;  // 0 .. 262144-8
        const float* src = (i < 131072) ? (wq + i) : (wk + (i - 131072));
        float4 a = *(const float4*)(src);
        float4 b = *(const float4*)(src + 4);
        uint4 r;
        r.x = f2b(a.x) | ((unsigned)f2b(a.y) << 16);
        r.y = f2b(a.z) | ((unsigned)f2b(a.w) << 16);
        r.z = f2b(b.x) | ((unsigned)f2b(b.y) << 16);
        r.w = f2b(b.z) | ((unsigned)f2b(b.w) << 16);
        *(uint4*)(wdst + i) = r;
        return;
    }
    int wave = tid >> 6, lane = tid & 63;
    int row = blockIdx.x * 4 + wave;
    size_t base = (size_t)row * DIN_ + lane * 8;
    float4 a = *(const float4*)(x + base);
    float4 b = *(const float4*)(x + base + 4);
    float4 wa = *(const float4*)(wvs + lane * 8);
    float4 wb = *(const float4*)(wvs + lane * 8 + 4);
    uint4 r;
    r.x = f2b(a.x) | ((unsigned)f2b(a.y) << 16);
    r.y = f2b(a.z) | ((unsigned)f2b(a.w) << 16);
    r.z = f2b(b.x) | ((unsigned)f2b(b.y) << 16);
    r.w = f2b(b.z) | ((unsigned)f2b(b.w) << 16);
    *(uint4*)(xb + base) = r;
    float d = a.x * wa.x + a.y * wa.y + a.z * wa.z + a.w * wa.w +
              b.x * wb.x + b.y * wb.y + b.z * wb.z + b.w * wb.w;
    for (int off = 1; off < 64; off <<= 1) d += __shfl_xor(d, off, 64);
    if (lane == 0) vw[row] = d + *bvs;  // bvs folded in HERE (only here)
}

// ---------------- Q,K GEMM — r14: BK=64 double-buffered 2-phase pipeline -----
__global__ __launch_bounds__(256, 2) void qkv_kernel(
    const unsigned short* __restrict__ xb, const unsigned short* __restrict__ wb,
    const float* __restrict__ bq, const float* __restrict__ bk,
    unsigned short* __restrict__ qo, unsigned short* __restrict__ ko) {
    __shared__ unsigned short alds[2][128 * 64];  // 16 KB per buffer
    __shared__ unsigned short blds[2][128 * 64];  // total 64 KB -> 2 blocks/CU
    const int g = blockIdx.x;
    const int xcd = g & 7, t2 = g >> 3;
    const int colBlk = t2 & 3, rowGrp = t2 >> 2;
    const int rowBlk = rowGrp * 8 + xcd;
    const int tid = threadIdx.x;
    const int wave = tid >> 6, lane = tid & 63, quad = lane >> 4, l16 = lane & 15;
    const int wr = wave >> 1, wc = wave & 1;
    const int row0 = rowBlk * 128, col0 = colBlk * 128;
    const int sw3 = l16 & 7;

    floatx4 acc[4][4];
#pragma unroll
    for (int i = 0; i < 4; ++i)
#pragma unroll
        for (int j = 0; j < 4; ++j) acc[i][j] = (floatx4){0.f, 0.f, 0.f, 0.f};

    const int gseg = (lane & 7) ^ (lane >> 3);
    const unsigned short* ag = xb + (size_t)(row0 + wave * 8 + (lane >> 3)) * DIN_ + gseg * 8;
    const unsigned short* bg = wb + (size_t)(col0 + wave * 8 + (lane >> 3)) * DIN_ + gseg * 8;

    // prologue: stage K-step 0 into buffer 0
#pragma unroll
    for (int i = 0; i < 4; ++i) {
        load_lds16(ag + (size_t)i * 32 * DIN_, &alds[0][wave * 512 + i * 2048]);
        load_lds16(bg + (size_t)i * 32 * DIN_, &blds[0][wave * 512 + i * 2048]);
    }
    __syncthreads();

#pragma unroll 1
    for (int t = 0; t < 8; ++t) {
        const unsigned short* al = (t & 1) ? alds[1] : alds[0];
        const unsigned short* bl = (t & 1) ? blds[1] : blds[0];
        unsigned short* aln = (t & 1) ? &alds[0][0] : &alds[1][0];
        unsigned short* bln = (t & 1) ? &blds[0][0] : &blds[1][0];
        if (t < 7) {
            size_t koff = (size_t)(t + 1) * 64;
#pragma unroll
            for (int i = 0; i < 4; ++i) {
                load_lds16(ag + (size_t)i * 32 * DIN_ + koff, aln + wave * 512 + i * 2048);
                load_lds16(bg + (size_t)i * 32 * DIN_ + koff, bln + wave * 512 + i * 2048);
            }
        }
#pragma unroll
        for (int h = 0; h < 2; ++h) {
            short8 af[4], bf[4];
#pragma unroll
            for (int f = 0; f < 4; ++f) {
                int ar = wr * 64 + f * 16 + l16;
                int br = wc * 64 + f * 16 + l16;
                int s  = (h * 4 + quad) ^ sw3;  // read-side swizzle (row&7 == l16&7)
                af[f] = *(const short8*)&al[(size_t)ar * 64 + s * 8];
                bf[f] = *(const short8*)&bl[(size_t)br * 64 + s * 8];
            }
#pragma unroll
            for (int i = 0; i < 4; ++i)
#pragma unroll
                for (int j = 0; j < 4; ++j)
                    acc[i][j] = __builtin_amdgcn_mfma_f32_16x16x32_bf16(af[i], bf[j], acc[i][j], 0, 0, 0);
        }
        __syncthreads();
    }

#pragma unroll
    for (int j = 0; j < 4; ++j) {
        int col = col0 + wc * 64 + j * 16 + l16;
        unsigned short* dst = (col < 256) ? qo : ko;
        float bias = (col < 256) ? bq[col] : bk[col - 256];
        int c = col & 255;
#pragma unroll
        for (int i = 0; i < 4; ++i)
#pragma unroll
            for (int r = 0; r < 4; ++r) {
                int row = row0 + wr * 64 + i * 16 + quad * 4 + r;
                dst[(size_t)row * DOUT_ + c] = f2b(acc[i][j][r] + bias);
            }
    }
}

// ---------------- gated flash attention — r20 (BEST build, restored) ---------
// Final model: LDS staging is REQUIRED (r26 direct-L2 refuted: 64KB/CU chunk
// > 32KB L1 -> every kf load ~200cy L2 latency, attn 69us). r20's ~21us =
// 16 chunks x (MFMA ~310cy + barrier/vmcnt-drain exposed at 2 waves/SIMD);
// three structures (r20/r22/r24) converge here; qf[4][8] register wall
// twice-confirmed; T15 gate-under-MFMA + gtab x32 + swizzled coop staging.
__global__ __launch_bounds__(512, 2) void attn_kernel(
    const unsigned short* __restrict__ q, const unsigned short* __restrict__ k,
    const float* __restrict__ vw, const int* __restrict__ pr,
    const float* __restrict__ rank_emb, const float* __restrict__ rank_w,
    const float* __restrict__ bs, float* __restrict__ out) {
    const int g = blockIdx.x;
    const int b = g & 7, rblk = g >> 3;
    const int tid = threadIdx.x, wave = tid >> 6, lane = tid & 63;
    const int quad = lane >> 4, l16 = lane & 15;
    const int n0 = rblk * 64;
    const int rg = wave >> 2, ch = wave & 3;  // 2 row-groups x 4 col-quarters

    __shared__ unsigned short kbuf[2][32768];  // 2 x 64KB: [128 k-rows][256]
    __shared__ float gtab_r[NBUCK * 32];       // x32 replicated: bank = lane&31
    __shared__ float lL[8][32], wdL[8][32];

    for (int t = tid; t < NBUCK * 32; t += 512)  // scale * log2e folded in
        gtab_r[t] = 0.0625f * 1.44269504f /
                    (1.f + __expf(-rank_w[0] * rank_emb[t >> 5]));

    const unsigned short* qb = q + (size_t)b * N_ * DOUT_;
    const unsigned short* kb = k + (size_t)b * N_ * DOUT_;
    const float* vwb = vw + b * N_;
    const int* prb = pr + b * N_;
    const int l8 = lane & 7;
    const int l31 = lane & 31;

    // Q fragments: rows n0 + rg*32 + a*16 + l16 (a=0,1) — 64 VGPRs
    short8 qf[2][8];
#pragma unroll
    for (int a = 0; a < 2; ++a)
#pragma unroll
        for (int c = 0; c < 8; ++c)
            qf[a][c] = *(const short8*)(qb + (size_t)(n0 + rg * 32 + a * 16 + l16) * DOUT_ + c * 32 + quad * 8);

    float prn5[2][4];
#pragma unroll
    for (int a = 0; a < 2; ++a)
#pragma unroll
        for (int r = 0; r < 4; ++r)
            prn5[a][r] = (float)prb[n0 + rg * 32 + a * 16 + quad * 4 + r] * 0.2f;

    float lacc[2][4], wacc[2][4];
#pragma unroll
    for (int a = 0; a < 2; ++a)
#pragma unroll
        for (int r = 0; r < 4; ++r) { lacc[a][r] = 0.f; wacc[a][r] = 0.f; }

    // cooperative staging: thread (wave,lane) issue i -> LDS row i*16+wave*2+(lane>>5),
    // seg lane&31; global seg pre-XOR'd so LDS[row][s] = k[row][s ^ (row&7)].
    const int stg_rbase = wave * 2 + (lane >> 5);            // 0..15
    const int stg_gseg  = (lane & 31) ^ (stg_rbase & 7);
    const unsigned short* stg_src0 = kb + (size_t)stg_rbase * DOUT_ + stg_gseg * 8;
    unsigned short* sdst0 = &kbuf[0][wave * 512];            // +i*4096; lane*16B by HW
    unsigned short* sdst1 = &kbuf[1][wave * 512];

    auto stage = [&](int j, unsigned short* sdst) {
        const unsigned short* src = stg_src0 + (size_t)j * 128 * DOUT_;
#pragma unroll
        for (int i = 0; i < 8; ++i)
            load_lds16(src + (size_t)i * 4096, sdst + i * 4096);
    };
    auto mfma = [&](floatx4 (&s)[2][2], const unsigned short* buf) {
#pragma unroll
        for (int a = 0; a < 2; ++a)
#pragma unroll
            for (int cf = 0; cf < 2; ++cf) s[a][cf] = (floatx4){0.f, 0.f, 0.f, 0.f};
        __builtin_amdgcn_s_setprio(1);
#pragma unroll
        for (int c = 0; c < 8; ++c) {
            int seg = (c * 4 + quad) ^ l8;  // row&7 == l16&7 == l8 for both cf
            short8 kf0 = *(const short8*)&buf[(size_t)(ch * 32 + l16) * 256 + seg * 8];
            short8 kf1 = *(const short8*)&buf[(size_t)(ch * 32 + 16 + l16) * 256 + seg * 8];
            s[0][0] = __builtin_amdgcn_mfma_f32_16x16x32_bf16(qf[0][c], kf0, s[0][0], 0, 0, 0);
            s[1][0] = __builtin_amdgcn_mfma_f32_16x16x32_bf16(qf[1][c], kf0, s[1][0], 0, 0, 0);
            s[0][1] = __builtin_amdgcn_mfma_f32_16x16x32_bf16(qf[0][c], kf1, s[0][1], 0, 0, 0);
            s[1][1] = __builtin_amdgcn_mfma_f32_16x16x32_bf16(qf[1][c], kf1, s[1][1], 0, 0, 0);
        }
        __builtin_amdgcn_s_setprio(0);
    };
    auto gate = [&](floatx4 (&s)[2][2], int pm0, int pm1, float w0, float w1) {
        float pm5_0 = (float)pm0 * 0.2f, pm5_1 = (float)pm1 * 0.2f;
#pragma unroll
        for (int a = 0; a < 2; ++a)
#pragma unroll
            for (int r = 0; r < 4; ++r) {
                float d0 = fabsf(prn5[a][r] - pm5_0);
                int i0 = (int)fminf(d0, 19.0f);
                float p0 = fexp2(s[a][0][r] * gtab_r[i0 * 32 + l31]);
                lacc[a][r] += p0;
                wacc[a][r] += p0 * w0;
                float d1 = fabsf(prn5[a][r] - pm5_1);
                int i1 = (int)fminf(d1, 19.0f);
                float p1 = fexp2(s[a][1][r] * gtab_r[i1 * 32 + l31]);
                lacc[a][r] += p1;
                wacc[a][r] += p1 * w1;
            }
    };

    floatx4 sA[2][2], sB[2][2];
    const int colq = ch * 32 + l16;  // +cf*16

    // ---- prologue -----------------------------------------------------------
    stage(0, sdst0);
    int   pmA0 = prb[colq], pmA1 = prb[colq + 16];
    float wA0 = vwb[colq], wA1 = vwb[colq + 16];
    __syncthreads();                       // gtab_r visible + chunk 0 staged
    stage(1, sdst1);
    int   pmB0 = prb[128 + colq], pmB1 = prb[128 + colq + 16];
    float wB0 = vwb[128 + colq], wB1 = vwb[128 + colq + 16];
    mfma(sA, kbuf[0]);                     // chunk 0
    __syncthreads();                       // chunk 1 staged; buf0 reads done

    // ---- steady state: compute j, gate j-1 (T15), stage j+1 ----------------
#pragma unroll 1
    for (int jj = 0; jj < 7; ++jj) {
        {   // compute 2jj+1 (buf1) -> sB ; gate 2jj (sA) ; stage 2jj+2 -> buf0
            int jn = 2 * jj + 2;
            stage(jn, sdst0);
            int   p0 = prb[jn * 128 + colq], p1 = prb[jn * 128 + colq + 16];
            float w0 = vwb[jn * 128 + colq], w1 = vwb[jn * 128 + colq + 16];
            mfma(sB, kbuf[1]);
            __builtin_amdgcn_sched_barrier(0);
            gate(sA, pmA0, pmA1, wA0, wA1);
            pmA0 = p0; pmA1 = p1; wA0 = w0; wA1 = w1;
            __syncthreads();
        }
        {   // compute 2jj+2 (buf0) -> sA ; gate 2jj+1 (sB) ; stage 2jj+3 -> buf1
            int jn = 2 * jj + 3;
            stage(jn, sdst1);
            int   p0 = prb[jn * 128 + colq], p1 = prb[jn * 128 + colq + 16];
            float w0 = vwb[jn * 128 + colq], w1 = vwb[jn * 128 + colq + 16];
            mfma(sA, kbuf[0]);
            __builtin_amdgcn_sched_barrier(0);
            gate(sB, pmB0, pmB1, wB0, wB1);
            pmB0 = p0; pmB1 = p1; wB0 = w0; wB1 = w1;
            __syncthreads();
        }
    }
    // ---- epilogue: chunk 15 -> sB ; gate 14 (sA) ; gate 15 (sB) -------------
    mfma(sB, kbuf[1]);
    __builtin_amdgcn_sched_barrier(0);
    gate(sA, pmA0, pmA1, wA0, wA1);
    gate(sB, pmB0, pmB1, wB0, wB1);

    // merge partials over the 16 column-lanes
#pragma unroll
    for (int off = 1; off < 16; off <<= 1) {
#pragma unroll
        for (int a = 0; a < 2; ++a)
#pragma unroll
            for (int r = 0; r < 4; ++r) {
                lacc[a][r] += __shfl_xor(lacc[a][r], off, 64);
                wacc[a][r] += __shfl_xor(wacc[a][r], off, 64);
            }
    }
    if (l16 == 0) {
#pragma unroll
        for (int a = 0; a < 2; ++a)
#pragma unroll
            for (int r = 0; r < 4; ++r) {
                int row = a * 16 + quad * 4 + r;   // 0..31 within wave's rows
                lL[wave][row]  = lacc[a][r];
                wdL[wave][row] = wacc[a][r];
            }
    }
    __syncthreads();
    if (tid < 64) {
        int rg2 = tid >> 5, sub = tid & 31;
        float l = 0.f, wd = 0.f;
#pragma unroll
        for (int c2 = 0; c2 < 4; ++c2) {
            l  += lL[rg2 * 4 + c2][sub];
            wd += wdL[rg2 * 4 + c2][sub];
        }
        float logit = wd / l + bs[0];   // bvs already inside vw
        out[(size_t)b * N_ + n0 + tid] = 1.f / (1.f + __expf(-logit));
    }
}

// ---------------- launch ----------------
extern "C" void kernel_launch(void* const* d_in, const int* in_sizes, int n_in,
                              void* d_out, int out_size, void* d_ws, size_t ws_size,
                              hipStream_t stream) {
    const float* x   = (const float*)d_in[0];
    const int*   pr  = (const int*)d_in[1];
    const float* Wq  = (const float*)d_in[2];
    const float* bq  = (const float*)d_in[3];
    const float* Wk  = (const float*)d_in[4];
    const float* bk  = (const float*)d_in[5];
    const float* Wv  = (const float*)d_in[6];
    const float* bv  = (const float*)d_in[7];
    const float* Ws  = (const float*)d_in[8];
    const float* bs  = (const float*)d_in[9];
    const float* remb = (const float*)d_in[10];
    const float* rw   = (const float*)d_in[11];
    float* out = (float*)d_out;

    char* ws = (char*)d_ws;
    unsigned short* xb  = (unsigned short*)ws;                    // 16,777,216 B
    unsigned short* wb  = (unsigned short*)(ws + 16777216);       //    524,288 B
    unsigned short* q   = (unsigned short*)(ws + 17301504);       //  8,388,608 B
    unsigned short* kk  = (unsigned short*)(ws + 25690112);       //  8,388,608 B
    float*          vwp = (float*)(ws + 34078720);                //     65,536 B
    float*          wvs = (float*)(ws + 34144256);                //      2,048 B
    float*          bvs = (float*)(ws + 34146304);                //          4 B

    hipLaunchKernelGGL(prep_kernel, dim3(4), dim3(256), 0, stream,
                       Wv, Ws, bv, wvs, bvs);
    hipLaunchKernelGGL(cvt_x_kernel, dim3(4224), dim3(256), 0, stream,
                       x, wvs, bvs, Wq, Wk, xb, wb, vwp);
    hipLaunchKernelGGL(qkv_kernel, dim3(512), dim3(256), 0, stream,
                       xb, wb, bq, bk, q, kk);
    hipLaunchKernelGGL(attn_kernel, dim3(256), dim3(512), 0, stream,
                       q, kk, vwp, pr, remb, rw, bs, out);
}